// Round 1
// baseline (3425.170 us; speedup 1.0000x reference)
//
#include <hip/hip_runtime.h>
#include <hip/hip_bf16.h>

typedef unsigned short u16;
typedef unsigned int   u32;
typedef __attribute__((ext_vector_type(8))) short bf16x8;
typedef __attribute__((ext_vector_type(4))) float f32x4;

#define NH   16
#define SS   2048

__device__ __forceinline__ u16 bf16b(float f) {
  union { float f; u32 u; } v; v.f = f;
  u32 r = (v.u + 0x7fffu + ((v.u >> 16) & 1u)) >> 16;
  return (u16)r;
}
__device__ __forceinline__ float bf2f(u16 v) {
  union { u32 u; float f; } x; x.u = (u32)v << 16; return x.f;
}
__device__ __forceinline__ f32x4 mfma16(bf16x8 a, bf16x8 b, f32x4 c) {
  return __builtin_amdgcn_mfma_f32_16x16x32_bf16(a, b, c, 0, 0, 0);
}

// ---------------------------------------------------------------- zero-fill (ws-too-small signature)
__global__ __launch_bounds__(256) void zerok(float* __restrict__ p, long n)
{
  long i = ((long)blockIdx.x * 256 + threadIdx.x) * 4;
  if (i < n) { p[i] = 0.f; p[i+1] = 0.f; p[i+2] = 0.f; p[i+3] = 0.f; }
}

// ---------------------------------------------------------------- cast fp32->bf16
__global__ __launch_bounds__(256) void castk(const float* __restrict__ src,
                                             u16* __restrict__ dst, long n)
{
  long i = ((long)blockIdx.x * 256 + threadIdx.x) * 4;
  if (i >= n) return;
  const float4 f = *(const float4*)(src + i);
  uint2 v;
  v.x = (u32)bf16b(f.x) | ((u32)bf16b(f.y) << 16);
  v.y = (u32)bf16b(f.z) | ((u32)bf16b(f.w) << 16);
  *(uint2*)(dst + i) = v;
}

// ---------------------------------------------------------------- split wkv_b
// T1[h][c][d] = wkv_b[(h*256+d)*512 + c]   (nope, transposed -> B^T GEMM form)
// Wv[h][d][c] = wkv_b[(h*256+128+d)*512+c] (v part)
__global__ __launch_bounds__(256) void wsplit(const float* __restrict__ wb,
                                              u16* __restrict__ T1, u16* __restrict__ Wv)
{
  const long i = (long)blockIdx.x * 256 + threadIdx.x;   // < 16*65536
  const int h   = (int)(i >> 16);
  const int rem = (int)(i & 65535);
  { const int c = rem >> 7, d = rem & 127;
    T1[i] = bf16b(wb[((long)(h * 256 + d)) * 512 + c]); }
  { const int d = rem >> 9, c = rem & 511;
    Wv[i] = bf16b(wb[((long)(h * 256 + 128 + d)) * 512 + c]); }
}

// ---------------------------------------------------------------- generic bf16 GEMM  C = A @ W^T
template<int OUTBF>
__global__ __launch_bounds__(256, 2)
void gemm_bt(const u16* __restrict__ A, const u16* __restrict__ W, void* __restrict__ Cout,
             int M, int N, int K, int lda, int ldw, int ldc,
             long aStride, long wStride, long cStride)
{
  __shared__ u16 As[128 * 40];
  __shared__ u16 Bs[128 * 40];
  const int tid = threadIdx.x;
  const int wave = tid >> 6, lane = tid & 63, g = lane >> 4, l15 = lane & 15;
  const int z = blockIdx.z;
  A += (long)z * aStride;  W += (long)z * wStride;
  const long cOff = (long)z * cStride;
  const int m0 = blockIdx.y * 128, n0 = blockIdx.x * 128;
  const int mq = (wave >> 1) * 64, nq = (wave & 1) * 64;
  const int srow = tid >> 1, scol = (tid & 1) * 16;

  const f32x4 fzero = {0.f, 0.f, 0.f, 0.f};
  f32x4 acc[4][4];
#pragma unroll
  for (int i = 0; i < 4; i++)
#pragma unroll
    for (int j = 0; j < 4; j++) acc[i][j] = fzero;

  for (int k0 = 0; k0 < K; k0 += 32) {
    const u16* aSrc = A + (long)(m0 + srow) * lda + k0 + scol;
    uint4 av0 = *(const uint4*)aSrc;
    uint4 av1 = *(const uint4*)(aSrc + 8);
    uint4 bv0 = make_uint4(0, 0, 0, 0), bv1 = make_uint4(0, 0, 0, 0);
    if (n0 + srow < N) {
      const u16* wSrc = W + (long)(n0 + srow) * ldw + k0 + scol;
      bv0 = *(const uint4*)wSrc;
      bv1 = *(const uint4*)(wSrc + 8);
    }
    __syncthreads();
    *(uint4*)&As[srow * 40 + scol]     = av0;
    *(uint4*)&As[srow * 40 + scol + 8] = av1;
    *(uint4*)&Bs[srow * 40 + scol]     = bv0;
    *(uint4*)&Bs[srow * 40 + scol + 8] = bv1;
    __syncthreads();

    bf16x8 af[4], bfr[4];
#pragma unroll
    for (int i = 0; i < 4; i++) af[i]  = *(const bf16x8*)&As[(mq + i * 16 + l15) * 40 + g * 8];
#pragma unroll
    for (int j = 0; j < 4; j++) bfr[j] = *(const bf16x8*)&Bs[(nq + j * 16 + l15) * 40 + g * 8];
#pragma unroll
    for (int i = 0; i < 4; i++)
#pragma unroll
      for (int j = 0; j < 4; j++)
        acc[i][j] = mfma16(af[i], bfr[j], acc[i][j]);
  }

#pragma unroll
  for (int i = 0; i < 4; i++) {
    const int r0 = m0 + mq + i * 16 + g * 4;
#pragma unroll
    for (int j = 0; j < 4; j++) {
      const int c = n0 + nq + j * 16 + l15;
      if (c < N) {
#pragma unroll
        for (int r = 0; r < 4; r++) {
          const long idx = cOff + (long)(r0 + r) * ldc + c;
          if (OUTBF) ((u16*)Cout)[idx]   = bf16b(acc[i][j][r]);
          else       ((float*)Cout)[idx] = acc[i][j][r];
        }
      }
    }
  }
}

// ---------------------------------------------------------------- q rope pack (bf16 q in, bf16 roped qpe out)
__global__ __launch_bounds__(256) void qpack(const u16* __restrict__ q,
                                             const float* __restrict__ angles,
                                             u16* __restrict__ qpe)
{
  const int s = blockIdx.x;
  const int sseq = s & (SS - 1);
  const int tid = threadIdx.x;
#pragma unroll
  for (int pp = 0; pp < 2; pp++) {
    const int p = tid * 2 + pp;           // 0..511 pair index
    const int h = p >> 5, j = p & 31;
    const float xr = bf2f(q[(long)s * 3072 + h * 192 + 128 + 2 * j]);
    const float xi = bf2f(q[(long)s * 3072 + h * 192 + 128 + 2 * j + 1]);
    float sn, cs;
    __sincosf(angles[sseq * 32 + j], &sn, &cs);
    const u32 pk = (u32)bf16b(xr * cs - xi * sn) | ((u32)bf16b(xr * sn + xi * cs) << 16);
    *(u32*)(qpe + ((long)s * NH + h) * 64 + 2 * j) = pk;
  }
}

// ---------------------------------------------------------------- kv pack: rmsnorm(kv_c)->bf16, rope(k_pe)->bf16
__global__ __launch_bounds__(256) void kvpack(const u16* __restrict__ kv,
                                              const float* __restrict__ angles,
                                              const float* __restrict__ kvw,
                                              u16* __restrict__ cb, u16* __restrict__ kpe)
{
  const int row = blockIdx.x * 4 + (threadIdx.x >> 6);
  const int lane = threadIdx.x & 63;
  const int sseq = row & (SS - 1);
  const u16* src = kv + (long)row * 576;
  float v[8]; float ss = 0.f;
#pragma unroll
  for (int j = 0; j < 8; j++) { float t = bf2f(src[lane + j * 64]); v[j] = t; ss += t * t; }
#pragma unroll
  for (int d = 1; d < 64; d <<= 1) ss += __shfl_xor(ss, d, 64);
  const float rn = 1.0f / sqrtf(ss * (1.f / 512.f) + 1e-6f);
#pragma unroll
  for (int j = 0; j < 8; j++)
    cb[(long)row * 512 + lane + j * 64] = bf16b(v[j] * rn * kvw[lane + j * 64]);
  if (lane < 32) {
    const float xr = bf2f(src[512 + 2 * lane]), xi = bf2f(src[512 + 2 * lane + 1]);
    float sn, cs;
    __sincosf(angles[sseq * 32 + lane], &sn, &cs);
    const u32 pk = (u32)bf16b(xr * cs - xi * sn) | ((u32)bf16b(xr * sn + xi * cs) << 16);
    *(u32*)(kpe + (long)row * 64 + 2 * lane) = pk;
  }
}

// ---------------------------------------------------------------- MFMA flash attention
// Block: 64 q-rows of one (b,h); 4 waves x 16 rows. t-tile = 32 (no PV zero-pad).
// Ks chunk-major [kc 0..71][t' 0..31][8 u16], u16 idx = kc*256 + (t'*8 ^ ((kc&7)<<3)):
//   - stage writes (lanes=kc, fixed t'): slot16 = (t'&7)^(kc&7) -> 2-way, free
//   - S-phase b128 reads (fixed kc, lanes=t'): slot16 = (t'&7)^(kc&7) -> 2-way, free
// VT [c 0..511][t' 0..31], u16 idx = (c*32 + t') ^ ((c&7)<<3):
//   - PV b128 reads per phase hit 8 distinct 16B slots x2 -> free
//   - staging u32 scatter rotated by vcb so (c&7) varies across lanes -> 2-way
// K=32 PV uses all-real P columns (both n-tiles written to Ps each step), so the
// old zero-init of Ps/VT (R4 NaN guard) is no longer needed: no padded region exists.
__global__ __launch_bounds__(256, 2)
void attn_flash(const u16* __restrict__ qab, const u16* __restrict__ qpe,
                const u16* __restrict__ cb, const u16* __restrict__ kpe,
                u16* __restrict__ olat)
{
  __shared__ u16 Ks[72 * 32 * 8];   // 36864 B  [kc][t'][8], swizzled
  __shared__ u16 VT[512 * 32];      // 32768 B  [c][t'], swizzled
  __shared__ u16 Ps[4][16 * 40];    //  5120 B  per-wave P[s'][t' 0..31], cols 32..39 unused

  const int tid = threadIdx.x;
  const int wave = tid >> 6, lane = tid & 63;
  const int g = lane >> 4, l15 = lane & 15;
  const int bh = blockIdx.y, b = bh >> 4, h = bh & 15;
  const int bx = (int)gridDim.x - 1 - (int)blockIdx.x;   // heavy blocks dispatch first
  const int s0 = bx * 64;
  const int swave = s0 + wave * 16;
  const float NEG_INF = -__builtin_inff();
  const float SC = 0.07216878364870323f * 1.3688879454113936f * 1.3688879454113936f;

  // Q A-fragments: A[m=l15][k=g*8+j], k over 576 = 18 frags
  bf16x8 qf[18];
  {
    const u16* qa = qab + ((long)(b * SS + swave + l15) * NH + h) * 512;
#pragma unroll
    for (int f = 0; f < 16; f++) qf[f] = *(const bf16x8*)(qa + f * 32 + g * 8);
    const u16* qp = qpe + ((long)(b * SS + swave + l15) * NH + h) * 64;
    qf[16] = *(const bf16x8*)(qp + g * 8);
    qf[17] = *(const bf16x8*)(qp + 32 + g * 8);
  }

  const f32x4 fzero = {0.f, 0.f, 0.f, 0.f};
  f32x4 oacc[32];                 // O[s'=g*4+r][c=i*16+l15]
#pragma unroll
  for (int i = 0; i < 32; i++) oacc[i] = fzero;
  float m[4], l[4];
#pragma unroll
  for (int r = 0; r < 4; r++) { m[r] = NEG_INF; l[r] = 0.f; }

  const int nsteps  = 2 * bx + 2;
  const int lastact = 2 * bx + (wave >> 1);   // last 32-tile this wave needs

  const int vtp = tid >> 4;        // VT staging: t-pair 0..15
  const int vcb = tid & 15;        // VT staging: c-block (32 c each)

  for (int ts = 0; ts < nsteps; ++ts) {
    const int t0 = ts * 32;
    __syncthreads();
    // ---- stage Ks (c part): per iter each wave owns row t'=it*4+wave, lanes = kc 0..63
    {
#pragma unroll
      for (int it = 0; it < 8; ++it) {
        const int tp = it * 4 + wave;
        const uint4 v = *(const uint4*)(cb + ((long)(b * SS + t0 + tp)) * 512 + lane * 8);
        *(uint4*)&Ks[lane * 256 + ((tp * 8) ^ ((lane & 7) << 3))] = v;
      }
      // rope chunks kc 64..71: one chunk per thread
      { const int kcl = tid & 7, tp = tid >> 3;
        const uint4 v = *(const uint4*)(kpe + ((long)(b * SS + t0 + tp)) * 64 + kcl * 8);
        *(uint4*)&Ks[(64 + kcl) * 256 + ((tp * 8) ^ (kcl << 3))] = v;
      }
    }
    // ---- stage VT (transpose + XOR swizzle), rows t'=2*vtp,2*vtp+1, 32 c per thread
    {
      const u16* pa = cb + ((long)(b * SS + t0 + 2 * vtp)) * 512 + vcb * 32;
      const u16* pb = pa + 512;
#pragma unroll
      for (int half = 0; half < 2; ++half) {
        u16 ua[16], ub[16];
        *(uint4*)&ua[0] = ((const uint4*)pa)[half * 2 + 0];
        *(uint4*)&ua[8] = ((const uint4*)pa)[half * 2 + 1];
        *(uint4*)&ub[0] = ((const uint4*)pb)[half * 2 + 0];
        *(uint4*)&ub[8] = ((const uint4*)pb)[half * 2 + 1];
        const int cbase = vcb * 32 + half * 16;
#pragma unroll
        for (int jj = 0; jj < 16; ++jj) {
          const int j = (jj + vcb) & 15;       // rotate so (c&7) varies across lanes
          const int c = cbase + j;
          const u32 pk = (u32)ua[j] | ((u32)ub[j] << 16);
          *(u32*)&VT[(c * 32 + 2 * vtp) ^ ((c & 7) << 3)] = pk;
        }
      }
    }
    __syncthreads();
    if (ts > lastact) continue;        // wave-uniform; barriers still hit

    // ---- S = Q K^T : two 16-wide n-tiles (t' 0..15, 16..31)
    f32x4 sacc0 = fzero, sacc1 = fzero;
#pragma unroll
    for (int f = 0; f < 18; ++f) {
      const int kc = f * 4 + g;
      const int sw = (kc & 7) << 3;
      const bf16x8 k0 = *(const bf16x8*)&Ks[kc * 256 + ((l15 * 8) ^ sw)];
      const bf16x8 k1 = *(const bf16x8*)&Ks[kc * 256 + (((128 + l15 * 8)) ^ sw)];
      sacc0 = mfma16(qf[f], k0, sacc0);
      sacc1 = mfma16(qf[f], k1, sacc1);
    }

    // ---- online softmax (row s'=g*4+r owned by this lane's g-group)
    float alf[4];
#pragma unroll
    for (int r = 0; r < 4; ++r) {
      const int srow = swave + g * 4 + r;
      float v0 = sacc0[r] * SC;
      float v1 = sacc1[r] * SC;
      if (t0 + l15 > srow)      v0 = NEG_INF;
      if (t0 + 16 + l15 > srow) v1 = NEG_INF;
      float tm = fmaxf(v0, v1);
#pragma unroll
      for (int d = 1; d < 16; d <<= 1) tm = fmaxf(tm, __shfl_xor(tm, d, 64));
      const float mnew = fmaxf(m[r], tm);
      const float al = __expf(m[r] - mnew);   // ts=0: exp(-inf)=0
      const float p0 = __expf(v0 - mnew);     // masked: 0
      const float p1 = __expf(v1 - mnew);
      float rs = p0 + p1;
#pragma unroll
      for (int d = 1; d < 16; d <<= 1) rs += __shfl_xor(rs, d, 64);
      l[r] = l[r] * al + rs;
      m[r] = mnew;
      alf[r] = al;
      Ps[wave][(g * 4 + r) * 40 + l15]      = bf16b(p0);  // intra-wave LDS, no barrier
      Ps[wave][(g * 4 + r) * 40 + 16 + l15] = bf16b(p1);
    }

    // ---- deferred rescale: skip the 128-VALU pass when no row max moved
    const bool resc = (alf[0] != 1.f) | (alf[1] != 1.f) | (alf[2] != 1.f) | (alf[3] != 1.f);
    if (__any(resc)) {
#pragma unroll
      for (int i = 0; i < 32; ++i) {
        f32x4 o = oacc[i];
        o[0] *= alf[0]; o[1] *= alf[1]; o[2] *= alf[2]; o[3] *= alf[3];
        oacc[i] = o;
      }
    }

    // ---- O += P.V : A[m=s'][k=t' 0..31 all real], B[n=c][k=t'] from swizzled VT
    const bf16x8 paf = *(const bf16x8*)&Ps[wave][l15 * 40 + g * 8];
#pragma unroll
    for (int i = 0; i < 32; ++i) {
      const int c = i * 16 + l15;
      const bf16x8 vf = *(const bf16x8*)&VT[(c * 32 + g * 8) ^ ((c & 7) << 3)];
      oacc[i] = mfma16(paf, vf, oacc[i]);
    }
  }

  // ---- epilogue: O[s][c] / l[s]
  float linv[4];
#pragma unroll
  for (int r = 0; r < 4; ++r) linv[r] = 1.0f / l[r];
#pragma unroll
  for (int r = 0; r < 4; ++r) {
    u16* dst = olat + ((long)(b * SS + swave + g * 4 + r) * NH + h) * 512 + l15;
#pragma unroll
    for (int i = 0; i < 32; ++i)
      dst[i * 16] = bf16b(oacc[i][r] * linv[r]);
  }
}

// ---------------------------------------------------------------- launch
extern "C" void kernel_launch(void* const* d_in, const int* in_sizes, int n_in,
                              void* d_out, int out_size, void* d_ws, size_t ws_size,
                              hipStream_t stream)
{
  const float* x      = (const float*)d_in[0];
  const float* angles = (const float*)d_in[1];
  const float* wq     = (const float*)d_in[2];
  const float* wkv_a  = (const float*)d_in[3];
  const float* wkv_b  = (const float*)d_in[4];
  const float* wo     = (const float*)d_in[5];
  const float* kvw    = (const float*)d_in[6];

  // --- workspace plan (byte offsets; lifetimes audited against launch order) ---
  // Region A [0, 67108864): phase1 xb|kvb|wab -> phase2 qab -> phase3 ob
  // Region B [67108864, 134217728): phase1 qbf|T1|wqb -> phase2 olat
  // Persistent: wob, Wv, qpe, cbuf, kpeb.
  const size_t WS_NEED = 157810688;
  if (ws_size < WS_NEED) {           // observable signature: err == ref absmax (3.890625)
    zerok<<<dim3(8192), dim3(256), 0, stream>>>((float*)d_out, 8388608L);
    return;
  }
  char* base = (char*)d_ws;
  u16* xb   = (u16*)(base + 0);           // 16,777,216 B  [4096][2048]   dead after kv GEMM
  u16* kvb  = (u16*)(base + 16777216);    //  4,718,592 B  [4096][576]    dead after kvpack
  u16* wab  = (u16*)(base + 21495808);    //  2,359,296 B  [576][2048]    dead after kv GEMM
  u16* qab  = (u16*)(base + 0);           // 67,108,864 B  [4096][16][512]  (phase2 of A)
  u16* ob   = (u16*)(base + 0);           // 16,777,216 B  [4096][2048]     (phase3 of A)
  u16* qbf  = (u16*)(base + 67108864);    // 25,165,824 B  [4096][3072]   dead after absorb GEMM
  u16* T1   = (u16*)(base + 92274688);    //  2,097,152 B  [16][512][128] dead after absorb GEMM
  u16* wqb  = (u16*)(base + 94371840);    // 12,582,912 B  [3072][2048]   dead after q GEMM
  u16* olat = (u16*)(base + 67108864);    // 67,108,864 B  [4096][16][512]  (phase2 of B)
  u16* wob  = (u16*)(base + 134217728);   //  8,388,608 B  [2048][2048]
  u16* Wv   = (u16*)(base + 142606336);   //  2,097,152 B  [16][128][512]
  u16* qpe_ = (u16*)(base + 144703488);   //  8,388,608 B  [4096][16][64]
  u16* cbuf = (u16*)(base + 153092096);   //  4,194,304 B  [4096][512]
  u16* kpeb = (u16*)(base + 157286400);   //    524,288 B  [4096][64]

  castk<<<dim3(8192), dim3(256), 0, stream>>>(x, xb, 8388608L);
  castk<<<dim3(6144), dim3(256), 0, stream>>>(wq, wqb, 6291456L);
  castk<<<dim3(1152), dim3(256), 0, stream>>>(wkv_a, wab, 1179648L);
  castk<<<dim3(4096), dim3(256), 0, stream>>>(wo, wob, 4194304L);
  wsplit<<<dim3(4096), dim3(256), 0, stream>>>(wkv_b, T1, Wv);

  // q = x @ wq^T (bf16 out) ; kv = x @ wkv_a^T (bf16 out)
  gemm_bt<1><<<dim3(24, 32, 1), dim3(256), 0, stream>>>(
      xb, wqb, (void*)qbf, 4096, 3072, 2048, 2048, 2048, 3072, 0L, 0L, 0L);
  gemm_bt<1><<<dim3(5, 32, 1), dim3(256), 0, stream>>>(
      xb, wab, (void*)kvb, 4096, 576, 2048, 2048, 2048, 576, 0L, 0L, 0L);

  qpack<<<dim3(4096), dim3(256), 0, stream>>>(qbf, angles, qpe_);
  kvpack<<<dim3(1024), dim3(256), 0, stream>>>(kvb, angles, kvw, cbuf, kpeb);

  // q_abs[s][h][c] = q_nope[s][h][:] @ T1[h][c][:]  (A read in-place from qbf, per-head offset h*192)
  gemm_bt<1><<<dim3(4, 32, 16), dim3(256), 0, stream>>>(
      qbf, T1, (void*)qab, 4096, 512, 128, 3072, 128, 8192, 192L, 65536L, 512L);

  attn_flash<<<dim3(32, 32), dim3(256), 0, stream>>>(qab, qpe_, cbuf, kpeb, olat);

  // o[s][h][d] = olat[s][h][:] @ Wv[h][d][:]
  gemm_bt<1><<<dim3(1, 32, 16), dim3(256), 0, stream>>>(
      olat, Wv, (void*)ob, 4096, 128, 512, 8192, 512, 2048, 512L, 65536L, 128L);

  // out = ob @ wo^T
  gemm_bt<0><<<dim3(16, 32, 1), dim3(256), 0, stream>>>(
      ob, wob, d_out, 4096, 2048, 2048, 2048, 2048, 2048, 0L, 0L, 0L);
}

// Round 2
// 1690.944 us; speedup vs baseline: 2.0256x; 2.0256x over previous
//
#include <hip/hip_runtime.h>
#include <hip/hip_bf16.h>

typedef unsigned short u16;
typedef unsigned int   u32;
typedef __attribute__((ext_vector_type(8))) short bf16x8;
typedef __attribute__((ext_vector_type(4))) float f32x4;

#define NH   16
#define SS   2048

__device__ __forceinline__ u16 bf16b(float f) {
  union { float f; u32 u; } v; v.f = f;
  u32 r = (v.u + 0x7fffu + ((v.u >> 16) & 1u)) >> 16;
  return (u16)r;
}
__device__ __forceinline__ float bf2f(u16 v) {
  union { u32 u; float f; } x; x.u = (u32)v << 16; return x.f;
}
__device__ __forceinline__ f32x4 mfma16(bf16x8 a, bf16x8 b, f32x4 c) {
  return __builtin_amdgcn_mfma_f32_16x16x32_bf16(a, b, c, 0, 0, 0);
}
// async global->LDS DMA, 16B per lane: LDS dest = wave-uniform base + lane*16B,
// global src per-lane (carries the swizzle).
__device__ __forceinline__ void gl_lds16(const u16* g, u16* l) {
  __builtin_amdgcn_global_load_lds(
      (const __attribute__((address_space(1))) void*)g,
      (__attribute__((address_space(3))) void*)l, 16, 0, 0);
}

// ---------------------------------------------------------------- zero-fill (ws-too-small signature)
__global__ __launch_bounds__(256) void zerok(float* __restrict__ p, long n)
{
  long i = ((long)blockIdx.x * 256 + threadIdx.x) * 4;
  if (i < n) { p[i] = 0.f; p[i+1] = 0.f; p[i+2] = 0.f; p[i+3] = 0.f; }
}

// ---------------------------------------------------------------- cast fp32->bf16
__global__ __launch_bounds__(256) void castk(const float* __restrict__ src,
                                             u16* __restrict__ dst, long n)
{
  long i = ((long)blockIdx.x * 256 + threadIdx.x) * 4;
  if (i >= n) return;
  const float4 f = *(const float4*)(src + i);
  uint2 v;
  v.x = (u32)bf16b(f.x) | ((u32)bf16b(f.y) << 16);
  v.y = (u32)bf16b(f.z) | ((u32)bf16b(f.w) << 16);
  *(uint2*)(dst + i) = v;
}

// ---------------------------------------------------------------- split wkv_b
__global__ __launch_bounds__(256) void wsplit(const float* __restrict__ wb,
                                              u16* __restrict__ T1, u16* __restrict__ Wv)
{
  const long i = (long)blockIdx.x * 256 + threadIdx.x;   // < 16*65536
  const int h   = (int)(i >> 16);
  const int rem = (int)(i & 65535);
  { const int c = rem >> 7, d = rem & 127;
    T1[i] = bf16b(wb[((long)(h * 256 + d)) * 512 + c]); }
  { const int d = rem >> 9, c = rem & 511;
    Wv[i] = bf16b(wb[((long)(h * 256 + 128 + d)) * 512 + c]); }
}

// ---------------------------------------------------------------- generic bf16 GEMM  C = A @ W^T
template<int OUTBF>
__global__ __launch_bounds__(256, 2)
void gemm_bt(const u16* __restrict__ A, const u16* __restrict__ W, void* __restrict__ Cout,
             int M, int N, int K, int lda, int ldw, int ldc,
             long aStride, long wStride, long cStride)
{
  __shared__ u16 As[128 * 40];
  __shared__ u16 Bs[128 * 40];
  const int tid = threadIdx.x;
  const int wave = tid >> 6, lane = tid & 63, g = lane >> 4, l15 = lane & 15;
  const int z = blockIdx.z;
  A += (long)z * aStride;  W += (long)z * wStride;
  const long cOff = (long)z * cStride;
  const int m0 = blockIdx.y * 128, n0 = blockIdx.x * 128;
  const int mq = (wave >> 1) * 64, nq = (wave & 1) * 64;
  const int srow = tid >> 1, scol = (tid & 1) * 16;

  const f32x4 fzero = {0.f, 0.f, 0.f, 0.f};
  f32x4 acc[4][4];
#pragma unroll
  for (int i = 0; i < 4; i++)
#pragma unroll
    for (int j = 0; j < 4; j++) acc[i][j] = fzero;

  for (int k0 = 0; k0 < K; k0 += 32) {
    const u16* aSrc = A + (long)(m0 + srow) * lda + k0 + scol;
    uint4 av0 = *(const uint4*)aSrc;
    uint4 av1 = *(const uint4*)(aSrc + 8);
    uint4 bv0 = make_uint4(0, 0, 0, 0), bv1 = make_uint4(0, 0, 0, 0);
    if (n0 + srow < N) {
      const u16* wSrc = W + (long)(n0 + srow) * ldw + k0 + scol;
      bv0 = *(const uint4*)wSrc;
      bv1 = *(const uint4*)(wSrc + 8);
    }
    __syncthreads();
    *(uint4*)&As[srow * 40 + scol]     = av0;
    *(uint4*)&As[srow * 40 + scol + 8] = av1;
    *(uint4*)&Bs[srow * 40 + scol]     = bv0;
    *(uint4*)&Bs[srow * 40 + scol + 8] = bv1;
    __syncthreads();

    bf16x8 af[4], bfr[4];
#pragma unroll
    for (int i = 0; i < 4; i++) af[i]  = *(const bf16x8*)&As[(mq + i * 16 + l15) * 40 + g * 8];
#pragma unroll
    for (int j = 0; j < 4; j++) bfr[j] = *(const bf16x8*)&Bs[(nq + j * 16 + l15) * 40 + g * 8];
#pragma unroll
    for (int i = 0; i < 4; i++)
#pragma unroll
      for (int j = 0; j < 4; j++)
        acc[i][j] = mfma16(af[i], bfr[j], acc[i][j]);
  }

#pragma unroll
  for (int i = 0; i < 4; i++) {
    const int r0 = m0 + mq + i * 16 + g * 4;
#pragma unroll
    for (int j = 0; j < 4; j++) {
      const int c = n0 + nq + j * 16 + l15;
      if (c < N) {
#pragma unroll
        for (int r = 0; r < 4; r++) {
          const long idx = cOff + (long)(r0 + r) * ldc + c;
          if (OUTBF) ((u16*)Cout)[idx]   = bf16b(acc[i][j][r]);
          else       ((float*)Cout)[idx] = acc[i][j][r];
        }
      }
    }
  }
}

// ---------------------------------------------------------------- q rope pack
__global__ __launch_bounds__(256) void qpack(const u16* __restrict__ q,
                                             const float* __restrict__ angles,
                                             u16* __restrict__ qpe)
{
  const int s = blockIdx.x;
  const int sseq = s & (SS - 1);
  const int tid = threadIdx.x;
#pragma unroll
  for (int pp = 0; pp < 2; pp++) {
    const int p = tid * 2 + pp;           // 0..511 pair index
    const int h = p >> 5, j = p & 31;
    const float xr = bf2f(q[(long)s * 3072 + h * 192 + 128 + 2 * j]);
    const float xi = bf2f(q[(long)s * 3072 + h * 192 + 128 + 2 * j + 1]);
    float sn, cs;
    __sincosf(angles[sseq * 32 + j], &sn, &cs);
    const u32 pk = (u32)bf16b(xr * cs - xi * sn) | ((u32)bf16b(xr * sn + xi * cs) << 16);
    *(u32*)(qpe + ((long)s * NH + h) * 64 + 2 * j) = pk;
  }
}

// ---------------------------------------------------------------- kv pack
__global__ __launch_bounds__(256) void kvpack(const u16* __restrict__ kv,
                                              const float* __restrict__ angles,
                                              const float* __restrict__ kvw,
                                              u16* __restrict__ cb, u16* __restrict__ kpe)
{
  const int row = blockIdx.x * 4 + (threadIdx.x >> 6);
  const int lane = threadIdx.x & 63;
  const int sseq = row & (SS - 1);
  const u16* src = kv + (long)row * 576;
  float v[8]; float ss = 0.f;
#pragma unroll
  for (int j = 0; j < 8; j++) { float t = bf2f(src[lane + j * 64]); v[j] = t; ss += t * t; }
#pragma unroll
  for (int d = 1; d < 64; d <<= 1) ss += __shfl_xor(ss, d, 64);
  const float rn = 1.0f / sqrtf(ss * (1.f / 512.f) + 1e-6f);
#pragma unroll
  for (int j = 0; j < 8; j++)
    cb[(long)row * 512 + lane + j * 64] = bf16b(v[j] * rn * kvw[lane + j * 64]);
  if (lane < 32) {
    const float xr = bf2f(src[512 + 2 * lane]), xi = bf2f(src[512 + 2 * lane + 1]);
    float sn, cs;
    __sincosf(angles[sseq * 32 + lane], &sn, &cs);
    const u32 pk = (u32)bf16b(xr * cs - xi * sn) | ((u32)bf16b(xr * sn + xi * cs) << 16);
    *(u32*)(kpe + (long)row * 64 + 2 * lane) = pk;
  }
}

// ---------------------------------------------------------------- MFMA flash attention
// Block: 64 q-rows of one (b,h); 4 waves x 16 rows; t-tile = 16 (R0 skeleton).
// K tile double-buffered via global_load_lds DMA (linear LDS dest; content
// pre-swizzled on the per-lane GLOBAL address): physical KsD[t'][q] holds
// cb[t'][q ^ sw(t')], sw(t') = ((t'>>1)&7)<<3. Raw s_barrier + explicit
// vmcnt(0) at the consume point only -> prefetch DMA stays in flight across
// the whole compute phase (no compiler barrier-drain).
// VT (V^T for PV) built LDS->LDS from the resident K tile (no 2nd global
// read of cb). VT mapping bijective: phys = x ^ (((x>>9)&7)<<3) with
// x = c*32 + t'; write scatter is static-index (no runtime-indexed arrays ->
// no scratch, the R1 failure). All LDS access patterns verified 2-way-or-floor
// by bank arithmetic.
__global__ __launch_bounds__(256, 2)
void attn_flash(const u16* __restrict__ qab, const u16* __restrict__ qpe,
                const u16* __restrict__ cb, const u16* __restrict__ kpe,
                u16* __restrict__ olat)
{
  __shared__ u16 KsD[2][16 * 512];   // 32768 B  K c-part, dbuf, content-swizzled
  __shared__ u16 KrD[2][16 * 64];    //  4096 B  K rope,  dbuf, content-swizzled
  __shared__ u16 VT[512 * 32];       // 32768 B  [c][t'] bijective-swizzled; t' 16..31 stay 0
  __shared__ u16 Ps[4][16 * 40];     //  5120 B  per-wave P[s'][t'], cols 16..39 stay 0

  const int tid = threadIdx.x;
  const int wave = tid >> 6, lane = tid & 63;
  const int g = lane >> 4, l15 = lane & 15;
  const int bh = blockIdx.y, b = bh >> 4, h = bh & 15;
  const int bx = blockIdx.x;
  const int s0 = bx * 64;
  const int swave = s0 + wave * 16;
  const float NEG_INF = -__builtin_inff();
  const float SC = 0.07216878364870323f * 1.3688879454113936f * 1.3688879454113936f;

  // zero-init Ps pad cols and full VT (unwritten swizzle slots must be 0.0:
  // they feed PV's k=16..31 region where Ps is 0 -> 0*finite = 0)
  for (int idx = tid; idx < 4 * 16 * 40 / 2; idx += 256) ((u32*)Ps)[idx] = 0;
  for (int idx = tid; idx < 512 * 32 / 2;   idx += 256) ((u32*)VT)[idx] = 0;

  // Q A-fragments: A[m=l15][k=g*8+j], k over 576 = 18 frags
  bf16x8 qf[18];
  {
    const u16* qa = qab + ((long)(b * SS + swave + l15) * NH + h) * 512;
#pragma unroll
    for (int f = 0; f < 16; f++) qf[f] = *(const bf16x8*)(qa + f * 32 + g * 8);
    const u16* qp = qpe + ((long)(b * SS + swave + l15) * NH + h) * 64;
    qf[16] = *(const bf16x8*)(qp + g * 8);
    qf[17] = *(const bf16x8*)(qp + 32 + g * 8);
  }

  const f32x4 fzero = {0.f, 0.f, 0.f, 0.f};
  f32x4 oacc[32];                 // O[s'=g*4+r][c=i*16+l15]
#pragma unroll
  for (int i = 0; i < 32; i++) oacc[i] = fzero;
  float m[4], l[4];
#pragma unroll
  for (int r = 0; r < 4; r++) { m[r] = NEG_INF; l[r] = 0.f; }

  const int nsteps  = 4 * bx + 4;
  const int lastact = 4 * bx + wave;   // last tile this wave needs

  const int tp   = tid & 7;        // VT build: t-pair 0..7
  const int cblk = tid >> 3;       // VT build: c-block 0..31 (16 c each)

  // ---- DMA issue for tile at row-offset t0n into buffer `buf` (wave-divided)
  auto stage = [&](int t0n, int buf) {
#pragma unroll
    for (int it = 0; it < 4; ++it) {
      const int tr = it * 4 + wave;                       // K row 0..15, 4 per wave
      const int sw = ((tr >> 1) & 7) << 3;
      const u16* gp = cb + (long)(b * SS + t0n + tr) * 512 + ((lane * 8) ^ sw);
      gl_lds16(gp, &KsD[buf][tr * 512]);                  // lane fills 16B chunk lane
    }
    if (wave < 2) {                                        // rope: 8 rows per wave
      const int r0 = wave * 8;
      const int tr = r0 + (lane >> 3);
      const int sw = ((tr >> 1) & 7) << 3;
      const u16* gp = kpe + (long)(b * SS + t0n + tr) * 64 + (((lane & 7) * 8) ^ sw);
      gl_lds16(gp, &KrD[buf][r0 * 64]);
    }
  };

  stage(0, 0);                      // prologue: tile 0 -> buf 0

  for (int ts = 0; ts < nsteps; ++ts) {
    const int cur = ts & 1;
    const int t0 = ts * 16;
    // consume point: own DMA landed; barrier makes all waves' DMA + prior
    // compute (last readers of VT and KsD[cur^1]) visible.
    asm volatile("s_waitcnt vmcnt(0) lgkmcnt(0)" ::: "memory");
    __builtin_amdgcn_s_barrier();

    if (ts + 1 < nsteps) stage(t0 + 16, cur ^ 1);   // prefetch; in flight through compute

    // ---- build VT from resident K tile (LDS->LDS transpose, static scatter)
    {
      const u16* K0 = &KsD[cur][(2 * tp) * 512];
      const u16* K1 = &KsD[cur][(2 * tp + 1) * 512];
      const int swr  = (tp & 7) << 3;                 // sw(2tp) == sw(2tp+1)
      const int cb16 = cblk * 16;
      const bf16x8 alo = *(const bf16x8*)&K0[(cb16)     ^ swr];
      const bf16x8 ahi = *(const bf16x8*)&K0[(cb16 + 8) ^ swr];
      const bf16x8 blo = *(const bf16x8*)&K1[(cb16)     ^ swr];
      const bf16x8 bhi = *(const bf16x8*)&K1[(cb16 + 8) ^ swr];
#pragma unroll
      for (int j = 0; j < 16; ++j) {                  // j static -> register extracts
        const int c = cb16 + j;
        const u16 ua = (u16)((j < 8) ? alo[j] : ahi[j - 8]);
        const u16 ub = (u16)((j < 8) ? blo[j] : bhi[j - 8]);
        *(u32*)&VT[(c * 32 + 2 * tp) ^ ((cblk & 7) << 3)] = (u32)ua | ((u32)ub << 16);
      }
    }
    asm volatile("s_waitcnt lgkmcnt(0)" ::: "memory");   // VT writes done (vmcnt untouched!)
    __builtin_amdgcn_s_barrier();

    if (ts > lastact) continue;        // wave-uniform; barriers still hit each iter

    // ---- S = Q K^T : dual accumulators halve the dependent-MFMA chain
    const int swl = ((l15 >> 1) & 7) << 3;
    const u16* KsC = &KsD[cur][l15 * 512];
    const u16* KrC = &KrD[cur][l15 * 64];
    f32x4 sacc = fzero, sacc2 = fzero;
#pragma unroll
    for (int f = 0; f < 16; f += 2) {
      const bf16x8 k0 = *(const bf16x8*)&KsC[((f    ) * 32 + g * 8) ^ swl];
      const bf16x8 k1 = *(const bf16x8*)&KsC[((f + 1) * 32 + g * 8) ^ swl];
      sacc  = mfma16(qf[f],     k0, sacc);
      sacc2 = mfma16(qf[f + 1], k1, sacc2);
    }
    {
      const bf16x8 k0 = *(const bf16x8*)&KrC[(     g * 8) ^ swl];
      const bf16x8 k1 = *(const bf16x8*)&KrC[(32 + g * 8) ^ swl];
      sacc  = mfma16(qf[16], k0, sacc);
      sacc2 = mfma16(qf[17], k1, sacc2);
    }

    // ---- online softmax with defer-max (THR=8): keep old m unless tile max
    // jumps by >8 -> rescale pass (below) skipped on most steps.
    float alf[4]; bool resc = false;
#pragma unroll
    for (int r = 0; r < 4; ++r) {
      const int srow = swave + g * 4 + r;
      float v = (sacc[r] + sacc2[r]) * SC;
      if (t0 + l15 > srow) v = NEG_INF;
      float tm = v;
#pragma unroll
      for (int d = 1; d < 16; d <<= 1) tm = fmaxf(tm, __shfl_xor(tm, d, 64));
      const float mnew = (tm > m[r] + 8.f) ? tm : m[r];   // m=-inf: -inf+8=-inf -> take tm
      const float al = __expf(m[r] - mnew);               // 1.0 when unchanged
      const float p  = __expf(v - mnew);                  // bounded by e^8; masked: 0
      float rs = p;
#pragma unroll
      for (int d = 1; d < 16; d <<= 1) rs += __shfl_xor(rs, d, 64);
      l[r] = l[r] * al + rs;
      resc |= (mnew != m[r]);
      m[r] = mnew;
      alf[r] = al;
      Ps[wave][(g * 4 + r) * 40 + l15] = bf16b(p);   // intra-wave LDS, no barrier
    }

    // ---- gated rescale (skipped when no row max moved anywhere in the wave)
    if (__any((int)resc)) {
#pragma unroll
      for (int i = 0; i < 32; ++i) {
        f32x4 o = oacc[i];
        o[0] *= alf[0]; o[1] *= alf[1]; o[2] *= alf[2]; o[3] *= alf[3];
        oacc[i] = o;
      }
    }

    // ---- O += P.V : A[m=s'][k=t' (0-pad 16..31)], B from bijective-swizzled VT
    const bf16x8 paf = *(const bf16x8*)&Ps[wave][l15 * 40 + g * 8];
#pragma unroll
    for (int i = 0; i < 32; ++i) {
      const int c = i * 16 + l15;
      const bf16x8 vf = *(const bf16x8*)&VT[(c * 32 + g * 8) ^ ((i & 7) << 3)];
      oacc[i] = mfma16(paf, vf, oacc[i]);
    }
  }

  // ---- epilogue: O[s][c] / l[s]
  float linv[4];
#pragma unroll
  for (int r = 0; r < 4; ++r) linv[r] = 1.0f / l[r];
#pragma unroll
  for (int r = 0; r < 4; ++r) {
    u16* dst = olat + ((long)(b * SS + swave + g * 4 + r) * NH + h) * 512 + l15;
#pragma unroll
    for (int i = 0; i < 32; ++i)
      dst[i * 16] = bf16b(oacc[i][r] * linv[r]);
  }
}

// ---------------------------------------------------------------- launch
extern "C" void kernel_launch(void* const* d_in, const int* in_sizes, int n_in,
                              void* d_out, int out_size, void* d_ws, size_t ws_size,
                              hipStream_t stream)
{
  const float* x      = (const float*)d_in[0];
  const float* angles = (const float*)d_in[1];
  const float* wq     = (const float*)d_in[2];
  const float* wkv_a  = (const float*)d_in[3];
  const float* wkv_b  = (const float*)d_in[4];
  const float* wo     = (const float*)d_in[5];
  const float* kvw    = (const float*)d_in[6];

  // --- workspace plan (byte offsets; lifetimes audited against launch order) ---
  const size_t WS_NEED = 157810688;
  if (ws_size < WS_NEED) {           // observable signature: err == ref absmax (3.890625)
    zerok<<<dim3(8192), dim3(256), 0, stream>>>((float*)d_out, 8388608L);
    return;
  }
  char* base = (char*)d_ws;
  u16* xb   = (u16*)(base + 0);           // 16,777,216 B  [4096][2048]   dead after kv GEMM
  u16* kvb  = (u16*)(base + 16777216);    //  4,718,592 B  [4096][576]    dead after kvpack
  u16* wab  = (u16*)(base + 21495808);    //  2,359,296 B  [576][2048]    dead after kv GEMM
  u16* qab  = (u16*)(base + 0);           // 67,108,864 B  [4096][16][512]  (phase2 of A)
  u16* ob   = (u16*)(base + 0);           // 16,777,216 B  [4096][2048]     (phase3 of A)
  u16* qbf  = (u16*)(base + 67108864);    // 25,165,824 B  [4096][3072]   dead after absorb GEMM
  u16* T1   = (u16*)(base + 92274688);    //  2,097,152 B  [16][512][128] dead after absorb GEMM
  u16* wqb  = (u16*)(base + 94371840);    // 12,582,912 B  [3072][2048]   dead after q GEMM
  u16* olat = (u16*)(base + 67108864);    // 67,108,864 B  [4096][16][512]  (phase2 of B)
  u16* wob  = (u16*)(base + 134217728);   //  8,388,608 B  [2048][2048]
  u16* Wv   = (u16*)(base + 142606336);   //  2,097,152 B  [16][128][512]
  u16* qpe_ = (u16*)(base + 144703488);   //  8,388,608 B  [4096][16][64]
  u16* cbuf = (u16*)(base + 153092096);   //  4,194,304 B  [4096][512]
  u16* kpeb = (u16*)(base + 157286400);   //    524,288 B  [4096][64]

  castk<<<dim3(8192), dim3(256), 0, stream>>>(x, xb, 8388608L);
  castk<<<dim3(6144), dim3(256), 0, stream>>>(wq, wqb, 6291456L);
  castk<<<dim3(1152), dim3(256), 0, stream>>>(wkv_a, wab, 1179648L);
  castk<<<dim3(4096), dim3(256), 0, stream>>>(wo, wob, 4194304L);
  wsplit<<<dim3(4096), dim3(256), 0, stream>>>(wkv_b, T1, Wv);

  // q = x @ wq^T (bf16 out) ; kv = x @ wkv_a^T (bf16 out)
  gemm_bt<1><<<dim3(24, 32, 1), dim3(256), 0, stream>>>(
      xb, wqb, (void*)qbf, 4096, 3072, 2048, 2048, 2048, 3072, 0L, 0L, 0L);
  gemm_bt<1><<<dim3(5, 32, 1), dim3(256), 0, stream>>>(
      xb, wab, (void*)kvb, 4096, 576, 2048, 2048, 2048, 576, 0L, 0L, 0L);

  qpack<<<dim3(4096), dim3(256), 0, stream>>>(qbf, angles, qpe_);
  kvpack<<<dim3(1024), dim3(256), 0, stream>>>(kvb, angles, kvw, cbuf, kpeb);

  // q_abs[s][h][c] = q_nope[s][h][:] @ T1[h][c][:]
  gemm_bt<1><<<dim3(4, 32, 16), dim3(256), 0, stream>>>(
      qbf, T1, (void*)qab, 4096, 512, 128, 3072, 128, 8192, 192L, 65536L, 512L);

  attn_flash<<<dim3(32, 32), dim3(256), 0, stream>>>(qab, qpe_, cbuf, kpeb, olat);

  // o[s][h][d] = olat[s][h][:] @ Wv[h][d][:]
  gemm_bt<1><<<dim3(1, 32, 16), dim3(256), 0, stream>>>(
      olat, Wv, (void*)ob, 4096, 128, 512, 8192, 512, 2048, 512L, 65536L, 128L);

  // out = ob @ wo^T
  gemm_bt<0><<<dim3(16, 32, 1), dim3(256), 0, stream>>>(
      ob, wob, d_out, 4096, 2048, 2048, 2048, 2048, 2048, 0L, 0L, 0L);
}